// Round 5
// baseline (544.883 us; speedup 1.0000x reference)
//
#include <hip/hip_runtime.h>
#include <hip/hip_bf16.h>
#include <math.h>

// Problem constants (CausalSelfAttention: B=4, S=2048, Dm=2048, H=16, Hd=128)
#define SEQ   2048
#define DM    2048
#define NH    16
#define HD    128
#define MROWS 8192   // B*S

typedef __bf16 bf16x8 __attribute__((ext_vector_type(8)));
typedef __bf16 bf16x4 __attribute__((ext_vector_type(4)));
typedef float  f32x4  __attribute__((ext_vector_type(4)));

#define MFMA16(a, b, c) __builtin_amdgcn_mfma_f32_16x16x32_bf16((a), (b), (c), 0, 0, 0)

__device__ __forceinline__ void g2l16(const void* g, void* l) {
    __builtin_amdgcn_global_load_lds(
        (const __attribute__((address_space(1))) void*)g,
        (__attribute__((address_space(3))) void*)l, 16, 0, 0);
}

// Compile-time memory fence + raw barrier: NO vmcnt drain in the loops.
#define SFENCE() asm volatile("" ::: "memory")
#define BARRIER() do { SFENCE(); __builtin_amdgcn_s_barrier(); SFENCE(); } while (0)

// ---------------------------------------------------------------------------
// Fused prep: blocks [0,16384): transpose+convert the 4 weights
//             blocks [16384, 24576): elementwise x fp32->bf16
// ---------------------------------------------------------------------------
__global__ void prep_fused(const float* __restrict__ x,
                           const float* __restrict__ s0,
                           const float* __restrict__ s1,
                           const float* __restrict__ s2,
                           const float* __restrict__ s3,
                           __bf16* __restrict__ xb,
                           __bf16* __restrict__ wdst) {
    const int bx = blockIdx.x;
    if (bx < 16384) {
        __shared__ float t[32][33];
        const int z = bx >> 12, rem = bx & 4095;
        const float* src = (z == 0) ? s0 : (z == 1) ? s1 : (z == 2) ? s2 : s3;
        __bf16* d = wdst + (size_t)z * DM * DM;
        const int c0 = (rem & 63) * 32, r0 = (rem >> 6) * 32;
        for (int i = threadIdx.y; i < 32; i += 8)
            t[i][threadIdx.x] = src[(size_t)(r0 + i) * DM + c0 + threadIdx.x];
        __syncthreads();
        for (int i = threadIdx.y; i < 32; i += 8)
            d[(size_t)(c0 + i) * DM + r0 + threadIdx.x] = (__bf16)t[threadIdx.x][i];
    } else {
        const int tid = threadIdx.y * 32 + threadIdx.x;
        const size_t i0 = (((size_t)(bx - 16384)) * 256 + tid) * 8;
        if (i0 + 8 <= (size_t)MROWS * DM) {
            f32x4 a = *(const f32x4*)(x + i0);
            f32x4 b = *(const f32x4*)(x + i0 + 4);
            bf16x8 o;
#pragma unroll
            for (int j = 0; j < 4; ++j) { o[j] = (__bf16)a[j]; o[4 + j] = (__bf16)b[j]; }
            *(bf16x8*)(xb + i0) = o;
        }
    }
}

// ---------------------------------------------------------------------------
// GEMM, 256x256 8-phase counted-vmcnt template (T1+T2+T3+T4+T5), now with
// DEEP staging: all four half-tiles of t+2 are issued at t (B halves at ph2,
// A halves at ph3) — nothing for t+1 is issued during t, so the once-per-tile
// vmcnt(8) waits on loads issued ~7 phases earlier (> HBM miss latency) and
// leaves t+2's 8 loads (4 half-tiles) in flight.
// Per-thread ledger (2 loads/stage call, 4 stage calls/iter = 8 loads):
//   prologue: t0 (8) + t1 (8) -> vmcnt(8) lands t0.
//   iter t:   ph2 stage B0,B1(t+2); ph3 stage A0,A1(t+2);
//             wait: t+2<NT ? vmcnt(8) (lands all of t+1) : vmcnt(0).
// WAR safety: B-halves of cur buffer fully read by ph1-bar2 -> staged ph2;
//             A-halves by ph2-bar2 -> staged ph3. Barrier skeleton unchanged.
// MODE 0: fused QKV (Bt=[3*DM,DM]); Q/K -> [2][B,H,S,D] bf16; V -> Vt[B,H,D,S].
// MODE 1: final proj, fp32 out [M,DM].
// ---------------------------------------------------------------------------
template <int MODE>
__global__ __launch_bounds__(512, 2) void gemm_bt(const __bf16* __restrict__ A,
                                                  const __bf16* __restrict__ Bt,
                                                  const float* __restrict__ b0,
                                                  const float* __restrict__ b1,
                                                  const float* __restrict__ b2,
                                                  void* __restrict__ Cout_,
                                                  __bf16* __restrict__ Vt_) {
    constexpr int K  = DM;
    constexpr int NT = K / 64;                 // 32 K-tiles
    __shared__ __align__(16) __bf16 smem[65536];   // 128 KiB
    const int tid  = threadIdx.x;
    const int wave = tid >> 6, lane = tid & 63;
    const int quad = lane >> 4, l16 = lane & 15;
    const int wm = (wave >> 2) * 128, wn = (wave & 3) * 64;

    // T1: bijective XCD swizzle (nwg % 8 == 0 for both modes)
    const int nwgx = gridDim.x;
    const int nwg  = nwgx * gridDim.y;
    const int wg   = blockIdx.y * nwgx + blockIdx.x;
    const int swzb = (wg & 7) * (nwg >> 3) + (wg >> 3);
    const int bm = (swzb % nwgx) * 256;
    const int bn = (swzb / nwgx) * 256;

    const int proj = (MODE == 0) ? (bn >> 11) : 0;              // block-uniform
    const float* bias = (MODE == 0) ? (proj == 0 ? b0 : (proj == 1 ? b1 : b2)) : b0;

    // staging: slot chunk c holds global chunk c^(row&7); row&7 == lane>>3 here
    const int r8   = lane >> 3;
    const int cSrc = (lane & 7) ^ r8;
    const __bf16* aSrc = A  + (size_t)(bm + wave * 8 + r8) * K + cSrc * 8;
    const __bf16* bSrc = Bt + (size_t)(bn + wave * 8 + r8) * K + cSrc * 8;
    const int ldsW = wave * 8 * 64;            // wave-uniform LDS base (elements)

    __bf16* As0 = smem;          __bf16* Bs0 = smem + 16384;
    __bf16* As1 = smem + 32768;  __bf16* Bs1 = smem + 49152;

    // one half-tile stage = 2 x g2l16 per thread (128 rows x 64 cols bf16)
    auto stage = [&](const __bf16* srcLane, __bf16* dstTile, int half, int t) {
#pragma unroll
        for (int q = 0; q < 2; ++q) {
            const int rr = half * 128 + q * 64;
            g2l16(srcLane + (size_t)rr * K + t * 64, dstTile + rr * 64 + ldsW);
        }
    };

    f32x4 acc[8][4];
#pragma unroll
    for (int i = 0; i < 8; ++i)
#pragma unroll
        for (int j = 0; j < 4; ++j) acc[i][j] = (f32x4){0.f, 0.f, 0.f, 0.f};

    // prologue: all of t0 and t1 in flight; vmcnt(8) lands t0 (t1's 8 remain)
    stage(bSrc, Bs0, 0, 0);
    stage(bSrc, Bs0, 1, 0);
    stage(aSrc, As0, 0, 0);
    stage(aSrc, As0, 1, 0);
    if (NT > 1) {
        stage(bSrc, Bs1, 0, 1);
        stage(bSrc, Bs1, 1, 1);
        stage(aSrc, As1, 0, 1);
        stage(aSrc, As1, 1, 1);
    }
    asm volatile("s_waitcnt vmcnt(8)" ::: "memory");
    BARRIER();

    const int swz8 = l16 & 7;
    bf16x8 ah[4][2], bh[4][2];

    for (int t = 0; t < NT; ++t) {
        __bf16* As  = (t & 1) ? As1 : As0;
        __bf16* Bs  = (t & 1) ? Bs1 : Bs0;

        // ---- phase 0: read a[0..3](x2kk) + b[0..1](x2kk); no staging
#pragma unroll
        for (int i = 0; i < 4; ++i)
#pragma unroll
            for (int kk = 0; kk < 2; ++kk)
                ah[i][kk] = *(const bf16x8*)(As + (wm + i * 16 + l16) * 64 +
                                             (((kk * 4 + quad) ^ swz8) * 8));
#pragma unroll
        for (int j = 0; j < 2; ++j)
#pragma unroll
            for (int kk = 0; kk < 2; ++kk)
                bh[j][kk] = *(const bf16x8*)(Bs + (wn + j * 16 + l16) * 64 +
                                             (((kk * 4 + quad) ^ swz8) * 8));
        BARRIER();
        __builtin_amdgcn_s_setprio(1);
#pragma unroll
        for (int i = 0; i < 4; ++i)
#pragma unroll
            for (int j = 0; j < 2; ++j) {
                acc[i][j] = MFMA16(ah[i][0], bh[j][0], acc[i][j]);
                acc[i][j] = MFMA16(ah[i][1], bh[j][1], acc[i][j]);
            }
        __builtin_amdgcn_s_setprio(0);
        BARRIER();

        // ---- phase 1: read b[2..3]; no staging
#pragma unroll
        for (int j = 2; j < 4; ++j)
#pragma unroll
            for (int kk = 0; kk < 2; ++kk)
                bh[j][kk] = *(const bf16x8*)(Bs + (wn + j * 16 + l16) * 64 +
                                             (((kk * 4 + quad) ^ swz8) * 8));
        BARRIER();
        __builtin_amdgcn_s_setprio(1);
#pragma unroll
        for (int i = 0; i < 4; ++i)
#pragma unroll
            for (int j = 2; j < 4; ++j) {
                acc[i][j] = MFMA16(ah[i][0], bh[j][0], acc[i][j]);
                acc[i][j] = MFMA16(ah[i][1], bh[j][1], acc[i][j]);
            }
        __builtin_amdgcn_s_setprio(0);
        BARRIER();

        // ---- phase 2: read a[4..7]; stage BOTH B halves of t+2 into cur buf
        //              (B-halves of cur buf fully consumed by ph1-bar2)
#pragma unroll
        for (int i = 0; i < 4; ++i)
#pragma unroll
            for (int kk = 0; kk < 2; ++kk)
                ah[i][kk] = *(const bf16x8*)(As + (wm + 64 + i * 16 + l16) * 64 +
                                             (((kk * 4 + quad) ^ swz8) * 8));
        if (t + 2 < NT) {
            stage(bSrc, Bs, 0, t + 2);
            stage(bSrc, Bs, 1, t + 2);
        }
        BARRIER();
        __builtin_amdgcn_s_setprio(1);
#pragma unroll
        for (int i = 0; i < 4; ++i)
#pragma unroll
            for (int j = 0; j < 2; ++j) {
                acc[4 + i][j] = MFMA16(ah[i][0], bh[j][0], acc[4 + i][j]);
                acc[4 + i][j] = MFMA16(ah[i][1], bh[j][1], acc[4 + i][j]);
            }
        __builtin_amdgcn_s_setprio(0);
        BARRIER();

        // ---- phase 3: stage BOTH A halves of t+2 (A reads done by ph2-bar2);
        //               MFMA; counted vmcnt BEFORE the barrier (lands t+1)
        if (t + 2 < NT) {
            stage(aSrc, As, 0, t + 2);
            stage(aSrc, As, 1, t + 2);
        }
        BARRIER();
        __builtin_amdgcn_s_setprio(1);
#pragma unroll
        for (int i = 0; i < 4; ++i)
#pragma unroll
            for (int j = 2; j < 4; ++j) {
                acc[4 + i][j] = MFMA16(ah[i][0], bh[j][0], acc[4 + i][j]);
                acc[4 + i][j] = MFMA16(ah[i][1], bh[j][1], acc[4 + i][j]);
            }
        __builtin_amdgcn_s_setprio(0);
        if (t + 2 < NT) asm volatile("s_waitcnt vmcnt(8)" ::: "memory");
        else            asm volatile("s_waitcnt vmcnt(0)" ::: "memory");
        BARRIER();
    }

    if (MODE == 0 && proj == 2) {
        // V epilogue: per-wave transpose 128(m) x 64(n) -> Vt[B,H,D,S].
        __bf16* wb = smem + wave * 4608;
        const int b_ = bm >> 11;
        const int p8 = lane >> 3, c8 = lane & 7;
#pragma unroll
        for (int ih = 0; ih < 2; ++ih) {
#pragma unroll
            for (int j = 0; j < 4; ++j) {
                const int n = (bn + wn + j * 16 + l16) & (DM - 1);
                const float bia = bias[n];
#pragma unroll
                for (int ii = 0; ii < 4; ++ii) {
                    bf16x4 pk;
#pragma unroll
                    for (int r = 0; r < 4; ++r)
                        pk[r] = (__bf16)(acc[ih * 4 + ii][j][r] + bia);
                    *(bf16x4*)(wb + (j * 16 + l16) * 72 + ii * 16 + quad * 4) = pk;
                }
            }
            // read rows along m, 16B-coalesced stores along s
#pragma unroll
            for (int p = 0; p < 8; ++p) {
                const int d_loc = p * 8 + p8;
                const int n = (bn + wn + d_loc) & (DM - 1);
                const int h = n >> 7, d = n & (HD - 1);
                bf16x8 v = *(const bf16x8*)(wb + d_loc * 72 + c8 * 8);
                const int s = (bm & (SEQ - 1)) + wm + ih * 64 + c8 * 8;
                *(bf16x8*)(Vt_ + ((size_t)((b_ * NH + h) * HD + d)) * SEQ + s) = v;
            }
        }
        return;
    }

    if (MODE == 0) {
        __bf16* out = (__bf16*)Cout_ + (size_t)proj * MROWS * DM;
#pragma unroll
        for (int i = 0; i < 8; ++i) {
            const int m = bm + wm + i * 16 + quad * 4;
            const int b_ = m >> 11, s0 = m & (SEQ - 1);
#pragma unroll
            for (int j = 0; j < 4; ++j) {
                const int n = (bn + wn + j * 16 + l16) & (DM - 1);
                const int h = n >> 7, d = n & (HD - 1);
                const float bia = bias[n];
#pragma unroll
                for (int r = 0; r < 4; ++r)
                    out[((size_t)((b_ * NH + h) * SEQ + s0 + r)) * HD + d] =
                        (__bf16)(acc[i][j][r] + bia);
            }
        }
    } else {
        float* out = (float*)Cout_;
#pragma unroll
        for (int i = 0; i < 8; ++i) {
            const int m = bm + wm + i * 16 + quad * 4;
#pragma unroll
            for (int j = 0; j < 4; ++j) {
                const int n = bn + wn + j * 16 + l16;
                const float bia = bias[n];
#pragma unroll
                for (int r = 0; r < 4; ++r)
                    out[(size_t)(m + r) * DM + n] = acc[i][j][r] + bia;
            }
        }
    }
}

// ---------------------------------------------------------------------------
// Flash attention fwd, causal — frozen from round 4 (XCD-locality decode:
// gid = 64a + 8b + c -> XCD c serves bh in [8c,8c+8); all 16 q-blocks of a
// bh pin to one XCD's L2). 128 q/block, 8 waves x 16 q, 1-deep K/V pipeline.
// ---------------------------------------------------------------------------
__global__ __launch_bounds__(512) void fa_fwd(const __bf16* __restrict__ Q,
                                              const __bf16* __restrict__ Kg,
                                              const __bf16* __restrict__ Vt,
                                              __bf16* __restrict__ O) {
    __shared__ __bf16 Ks[64 * 128];     // [key][d] swizzled       16KB
    __shared__ __bf16 Vs[128 * 64];     // [d][key] swizzled       16KB
    __shared__ __bf16 Pt[8][16 * 72];   // per-wave P^T as [q][key] 18KB
    const int tid  = threadIdx.x;
    const int wave = tid >> 6, lane = tid & 63;
    const int quad = lane >> 4, l16 = lane & 15;
    // XCD-locality decode: gid = 64a + 8b + c -> bx = 15-a, bh = c*8 + b
    const int gid = blockIdx.x;
    const int bx  = 15 - (gid >> 6);
    const int bh  = ((gid & 7) << 3) | ((gid >> 3) & 7);
    const int q0 = bx * 128;
    const int qrow0 = q0 + wave * 16;   // this wave's 16 query rows
    __bf16* Pw = &Pt[wave][0];

    // staging lambdas: 2 x g2l16 each; LDS slot chunk c holds global chunk
    // c^(row&7) (both-sides swizzle, rule #21)
    auto stageK = [&](int k0s) {
#pragma unroll
        for (int j = 0; j < 2; ++j) {
            const int reg  = wave * 2 + j;
            const int rowK = reg * 4 + (lane >> 4);           // 0..63
            const int cK   = (lane & 15) ^ (rowK & 7);        // 16B chunk 0..15
            g2l16(Kg + (size_t)(bh * SEQ + k0s + rowK) * HD + cK * 8, Ks + reg * 512);
        }
    };
    auto stageV = [&](int k0s) {
#pragma unroll
        for (int j = 0; j < 2; ++j) {
            const int reg  = wave * 2 + j;
            const int rowV = reg * 8 + (lane >> 3);           // 0..127
            const int cV   = (lane & 7) ^ (rowV & 7);         // 16B chunk 0..7
            g2l16(Vt + (size_t)(bh * HD + rowV) * SEQ + k0s + cV * 8, Vs + reg * 512);
        }
    };

    // Q B-fragments: lane holds Q[qrow0+l16][kc*32+quad*8..+7]
    bf16x8 qf[4];
    const __bf16* qrow = Q + (size_t)(bh * SEQ + qrow0 + l16) * HD;
#pragma unroll
    for (int kc = 0; kc < 4; ++kc) qf[kc] = *(const bf16x8*)(qrow + kc * 32 + quad * 8);

    float m_q = -INFINITY, l_q = 0.f;   // per-lane: query q = qrow0 + l16
    f32x4 oacc[8];                      // O^T: d = ot*16 + quad*4 + r, q = l16
#pragma unroll
    for (int ot = 0; ot < 8; ++ot) oacc[ot] = (f32x4){0.f, 0.f, 0.f, 0.f};

    const float sl2 = 0.08838834764831845f * 1.4426950408889634f;  // scale*log2(e)

    // prologue: tile 0 in flight; publish K(0), keep V(0) in flight
    stageK(0);
    stageV(0);
    asm volatile("s_waitcnt vmcnt(2)" ::: "memory");
    BARRIER();

    const int ntiles = bx * 2 + 2;      // keys up to q0+127
    for (int kt = 0; kt < ntiles; ++kt) {
        const int k0 = kt * 64;
        const bool work = (k0 <= qrow0 + 15);
        const int swz = l16 & 7;
        f32x4 st[4];

        // ---- S^T = K Q^T (scaled): tile t rows = keys t*16+quad*4+r, col q=l16
        if (work) {
            __builtin_amdgcn_s_setprio(1);
#pragma unroll
            for (int t = 0; t < 4; ++t) {
                f32x4 a = (f32x4){0.f, 0.f, 0.f, 0.f};
#pragma unroll
                for (int kc = 0; kc < 4; ++kc) {
                    bf16x8 kf = *(const bf16x8*)(Ks + (t * 16 + l16) * 128 +
                                                 (((kc * 4 + quad) ^ swz) * 8));
                    a = MFMA16(kf, qf[kc], a);        // A = K, B = Q
                }
#pragma unroll
                for (int r = 0; r < 4; ++r) st[t][r] = a[r] * sl2;
            }
            __builtin_amdgcn_s_setprio(0);
        }
        asm volatile("s_waitcnt lgkmcnt(0)" ::: "memory");  // own Ks reads done
        BARRIER();                                          // B1: Ks free
        if (kt + 1 < ntiles) stageK(k0 + 64);               // prefetch K(t+1)

        if (work) {
            // ---- causal mask (diagonal only lives in the last two tiles)
            if (kt >= ntiles - 2) {
                const int q = qrow0 + l16;
#pragma unroll
                for (int t = 0; t < 4; ++t)
#pragma unroll
                    for (int r = 0; r < 4; ++r) {
                        const int key = k0 + t * 16 + quad * 4 + r;
                        if (key > q) st[t][r] = -INFINITY;
                    }
            }
            // ---- online softmax over keys (regs + quads)
            float vm = st[0][0];
#pragma unroll
            for (int t = 0; t < 4; ++t)
#pragma unroll
                for (int r = 0; r < 4; ++r) vm = fmaxf(vm, st[t][r]);
            vm = fmaxf(vm, __shfl_xor(vm, 16));
            vm = fmaxf(vm, __shfl_xor(vm, 32));
            const float mn = fmaxf(m_q, vm);
            const float alpha = __builtin_amdgcn_exp2f(m_q - mn);
            m_q = mn;
            float ps = 0.f;
#pragma unroll
            for (int t = 0; t < 4; ++t)
#pragma unroll
                for (int r = 0; r < 4; ++r) {
                    const float p = __builtin_amdgcn_exp2f(st[t][r] - mn);
                    st[t][r] = p;
                    ps += p;
                }
            ps += __shfl_xor(ps, 16);
            ps += __shfl_xor(ps, 32);
            l_q = l_q * alpha + ps;
#pragma unroll
            for (int ot = 0; ot < 8; ++ot)
#pragma unroll
                for (int r = 0; r < 4; ++r) oacc[ot][r] *= alpha;

            // ---- P^T rows: lane writes 4 consecutive keys at row q=l16 (b64)
#pragma unroll
            for (int t = 0; t < 4; ++t) {
                bf16x4 pk;
#pragma unroll
                for (int r = 0; r < 4; ++r) pk[r] = (__bf16)st[t][r];
                *(bf16x4*)(Pw + l16 * 72 + t * 16 + quad * 4) = pk;
            }
        }
        // publish V(t): own V loads are the 2 oldest outstanding (K(t+1) stays)
        if (kt + 1 < ntiles) asm volatile("s_waitcnt vmcnt(2)" ::: "memory");
        else                 asm volatile("s_waitcnt vmcnt(0)" ::: "memory");
        BARRIER();                                          // B2: V(t) visible

        if (work) {
            // ---- O^T += V^T P^T
            __builtin_amdgcn_s_setprio(1);
#pragma unroll
            for (int kk = 0; kk < 2; ++kk) {
                bf16x8 pf = *(const bf16x8*)(Pw + l16 * 72 + kk * 32 + quad * 8);
#pragma unroll
                for (int ot = 0; ot < 8; ++ot) {
                    bf16x8 vf = *(const bf16x8*)(Vs + (ot * 16 + l16) * 64 +
                                                 (((kk * 4 + quad) ^ swz) * 8));
                    oacc[ot] = MFMA16(vf, pf, oacc[ot]);   // A = V^T, B = P^T
                }
            }
            __builtin_amdgcn_s_setprio(0);
        }
        asm volatile("s_waitcnt lgkmcnt(0)" ::: "memory");  // own Vs reads done
        BARRIER();                                          // B3: Vs free
        if (kt + 1 < ntiles) {
            stageV(k0 + 64);                                // prefetch V(t+1)
            asm volatile("s_waitcnt vmcnt(2)" ::: "memory");// K(t+1) landed
        }
        BARRIER();                                          // B4: K(t+1) visible
    }

    // epilogue: O[b, s=qrow0+l16, h*128 + d], d = ot*16 + quad*4 + r (8B stores)
    const int b = bh >> 4, h = bh & (NH - 1);
    const float inv = 1.0f / l_q;
    __bf16* orow = O + ((size_t)(b * SEQ + qrow0 + l16)) * DM + h * HD;
#pragma unroll
    for (int ot = 0; ot < 8; ++ot) {
        bf16x4 ov;
#pragma unroll
        for (int r = 0; r < 4; ++r) ov[r] = (__bf16)(oacc[ot][r] * inv);
        *(bf16x4*)(orow + ot * 16 + quad * 4) = ov;
    }
}

// ---------------------------------------------------------------------------
extern "C" void kernel_launch(void* const* d_in, const int* in_sizes, int n_in,
                              void* d_out, int out_size, void* d_ws, size_t ws_size,
                              hipStream_t stream) {
    (void)in_sizes; (void)n_in; (void)out_size; (void)ws_size;
    const float* x  = (const float*)d_in[0];
    const float* Wq = (const float*)d_in[1];
    const float* bq = (const float*)d_in[2];
    const float* Wk = (const float*)d_in[3];
    const float* bk = (const float*)d_in[4];
    const float* Wv = (const float*)d_in[5];
    const float* bv = (const float*)d_in[6];
    const float* Wo = (const float*)d_in[7];
    const float* bo = (const float*)d_in[8];

    char* ws = (char*)d_ws;
    const size_t WT = (size_t)DM * DM * 2;      // 8 MB per transposed bf16 weight
    const size_t XB = (size_t)MROWS * DM * 2;   // 33.5 MB per bf16 activation
    __bf16* WTs = (__bf16*)ws;                  // WqT;WkT;WvT;WoT contiguous
    __bf16* WoT = (__bf16*)(ws + 3 * WT);
    __bf16* xb  = (__bf16*)(ws + 4 * WT + 0 * XB);
    __bf16* Qb  = (__bf16*)(ws + 4 * WT + 1 * XB);  // Qb/Kb contiguous
    __bf16* Kb  = (__bf16*)(ws + 4 * WT + 2 * XB);
    __bf16* Vtb = (__bf16*)(ws + 4 * WT + 3 * XB);  // V written directly as [B,H,D,S]
    __bf16* Ob  = xb;   // x is dead after the QKV projection

    const dim3 tb(32, 8);
    prep_fused<<<16384 + 8192, tb, 0, stream>>>(x, Wq, Wk, Wv, Wo, xb, WTs);

    // Fused QKV projection: [8192,2048] x [2048,6144]; V lands pre-transposed
    gemm_bt<0><<<dim3(32, 24), 512, 0, stream>>>(xb, WTs, bq, bk, bv, Qb, Vtb);

    // 1-D grid, XCD-locality decode inside the kernel (16 q-tiles x 64 bh)
    fa_fwd<<<dim3(1024), 512, 0, stream>>>(Qb, Kb, Vtb, Ob);

    gemm_bt<1><<<dim3(32, 8), 512, 0, stream>>>(Ob, WoT, bo, nullptr, nullptr,
                                                (float*)d_out, nullptr);
}

// Round 6
// 528.339 us; speedup vs baseline: 1.0313x; 1.0313x over previous
//
#include <hip/hip_runtime.h>
#include <hip/hip_bf16.h>
#include <math.h>

// Problem constants (CausalSelfAttention: B=4, S=2048, Dm=2048, H=16, Hd=128)
#define SEQ   2048
#define DM    2048
#define NH    16
#define HD    128
#define MROWS 8192   // B*S

typedef __bf16 bf16x8 __attribute__((ext_vector_type(8)));
typedef __bf16 bf16x4 __attribute__((ext_vector_type(4)));
typedef float  f32x4  __attribute__((ext_vector_type(4)));

#define MFMA16(a, b, c) __builtin_amdgcn_mfma_f32_16x16x32_bf16((a), (b), (c), 0, 0, 0)

__device__ __forceinline__ void g2l16(const void* g, void* l) {
    __builtin_amdgcn_global_load_lds(
        (const __attribute__((address_space(1))) void*)g,
        (__attribute__((address_space(3))) void*)l, 16, 0, 0);
}

// Compile-time memory fence + raw barrier: NO vmcnt drain in the loops.
#define SFENCE() asm volatile("" ::: "memory")
#define BARRIER() do { SFENCE(); __builtin_amdgcn_s_barrier(); SFENCE(); } while (0)

// ---------------------------------------------------------------------------
// Fused prep: blocks [0,16384): transpose+convert the 4 weights
//             blocks [16384, 24576): elementwise x fp32->bf16
// ---------------------------------------------------------------------------
__global__ void prep_fused(const float* __restrict__ x,
                           const float* __restrict__ s0,
                           const float* __restrict__ s1,
                           const float* __restrict__ s2,
                           const float* __restrict__ s3,
                           __bf16* __restrict__ xb,
                           __bf16* __restrict__ wdst) {
    const int bx = blockIdx.x;
    if (bx < 16384) {
        __shared__ float t[32][33];
        const int z = bx >> 12, rem = bx & 4095;
        const float* src = (z == 0) ? s0 : (z == 1) ? s1 : (z == 2) ? s2 : s3;
        __bf16* d = wdst + (size_t)z * DM * DM;
        const int c0 = (rem & 63) * 32, r0 = (rem >> 6) * 32;
        for (int i = threadIdx.y; i < 32; i += 8)
            t[i][threadIdx.x] = src[(size_t)(r0 + i) * DM + c0 + threadIdx.x];
        __syncthreads();
        for (int i = threadIdx.y; i < 32; i += 8)
            d[(size_t)(c0 + i) * DM + r0 + threadIdx.x] = (__bf16)t[threadIdx.x][i];
    } else {
        const int tid = threadIdx.y * 32 + threadIdx.x;
        const size_t i0 = (((size_t)(bx - 16384)) * 256 + tid) * 8;
        if (i0 + 8 <= (size_t)MROWS * DM) {
            f32x4 a = *(const f32x4*)(x + i0);
            f32x4 b = *(const f32x4*)(x + i0 + 4);
            bf16x8 o;
#pragma unroll
            for (int j = 0; j < 4; ++j) { o[j] = (__bf16)a[j]; o[4 + j] = (__bf16)b[j]; }
            *(bf16x8*)(xb + i0) = o;
        }
    }
}

// ---------------------------------------------------------------------------
// GEMM, 256x256 8-phase counted-vmcnt template — K-loop REVERTED to the
// round-4 schedule (measured 204 us; round-5 deep staging regressed to 222).
// NEW this round: XCD-REGION block mapping replaces the generic T1 swizzle.
//   XCD c owns bm-rows [4c, 4c+4) x ALL bn, inner order bm-major:
//   the XCD's A region = 4 panels = 4 MB = L2-resident for its lifetime ->
//   A fetched from HBM once globally; each B panel fetched once per XCD.
//   Predicted FETCH for MODE0: 405 MB -> ~240 MB. Bijective: c = wg&7,
//   q = wg>>3; bm_blk = c*4 + (q&3) in [0,32); bn_blk = q>>2.
// MODE 0: fused QKV (Bt=[3*DM,DM]); Q/K -> [2][B,H,S,D] bf16; V -> Vt[B,H,D,S].
// MODE 1: final proj, fp32 out [M,DM].
// ---------------------------------------------------------------------------
template <int MODE>
__global__ __launch_bounds__(512, 2) void gemm_bt(const __bf16* __restrict__ A,
                                                  const __bf16* __restrict__ Bt,
                                                  const float* __restrict__ b0,
                                                  const float* __restrict__ b1,
                                                  const float* __restrict__ b2,
                                                  void* __restrict__ Cout_,
                                                  __bf16* __restrict__ Vt_) {
    constexpr int K  = DM;
    constexpr int NT = K / 64;                 // 32 K-tiles
    __shared__ __align__(16) __bf16 smem[65536];   // 128 KiB
    const int tid  = threadIdx.x;
    const int wave = tid >> 6, lane = tid & 63;
    const int quad = lane >> 4, l16 = lane & 15;
    const int wm = (wave >> 2) * 128, wn = (wave & 3) * 64;

    // XCD-region mapping (requires gridDim.x == 32, nwg % 8 == 0; true both modes)
    const int wg = blockIdx.y * gridDim.x + blockIdx.x;
    const int xc = wg & 7;                 // XCD (dispatch round-robins on wg%8)
    const int q_ = wg >> 3;                // index within XCD
    const int bm = (xc * 4 + (q_ & 3)) * 256;   // 4 L2-resident A panels per XCD
    const int bn = (q_ >> 2) * 256;             // B panel streamed once per XCD

    const int proj = (MODE == 0) ? (bn >> 11) : 0;              // block-uniform
    const float* bias = (MODE == 0) ? (proj == 0 ? b0 : (proj == 1 ? b1 : b2)) : b0;

    // staging: slot chunk c holds global chunk c^(row&7); row&7 == lane>>3 here
    const int r8   = lane >> 3;
    const int cSrc = (lane & 7) ^ r8;
    const __bf16* aSrc = A  + (size_t)(bm + wave * 8 + r8) * K + cSrc * 8;
    const __bf16* bSrc = Bt + (size_t)(bn + wave * 8 + r8) * K + cSrc * 8;
    const int ldsW = wave * 8 * 64;            // wave-uniform LDS base (elements)

    __bf16* As0 = smem;          __bf16* Bs0 = smem + 16384;
    __bf16* As1 = smem + 32768;  __bf16* Bs1 = smem + 49152;

    // one half-tile stage = 2 x g2l16 per thread (128 rows x 64 cols bf16)
    auto stage = [&](const __bf16* srcLane, __bf16* dstTile, int half, int t) {
#pragma unroll
        for (int q = 0; q < 2; ++q) {
            const int rr = half * 128 + q * 64;
            g2l16(srcLane + (size_t)rr * K + t * 64, dstTile + rr * 64 + ldsW);
        }
    };

    f32x4 acc[8][4];
#pragma unroll
    for (int i = 0; i < 8; ++i)
#pragma unroll
        for (int j = 0; j < 4; ++j) acc[i][j] = (f32x4){0.f, 0.f, 0.f, 0.f};

    // prologue: B0(0) A0(0) B1(0) A1(0) B0(1) A0(1); tile0 landed after vmcnt(4)
    stage(bSrc, Bs0, 0, 0);
    stage(aSrc, As0, 0, 0);
    stage(bSrc, Bs0, 1, 0);
    stage(aSrc, As0, 1, 0);
    if (NT > 1) { stage(bSrc, Bs1, 0, 1); stage(aSrc, As1, 0, 1); }
    asm volatile("s_waitcnt vmcnt(4)" ::: "memory");
    BARRIER();

    const int swz8 = l16 & 7;
    bf16x8 ah[4][2], bh[4][2];

    for (int t = 0; t < NT; ++t) {
        __bf16* As  = (t & 1) ? As1 : As0;
        __bf16* Bs  = (t & 1) ? Bs1 : Bs0;
        __bf16* Asn = (t & 1) ? As0 : As1;
        __bf16* Bsn = (t & 1) ? Bs0 : Bs1;

        // ---- phase 0: read a[0..3](x2kk) + b[0..1](x2kk); stage B1(t+1)
#pragma unroll
        for (int i = 0; i < 4; ++i)
#pragma unroll
            for (int kk = 0; kk < 2; ++kk)
                ah[i][kk] = *(const bf16x8*)(As + (wm + i * 16 + l16) * 64 +
                                             (((kk * 4 + quad) ^ swz8) * 8));
#pragma unroll
        for (int j = 0; j < 2; ++j)
#pragma unroll
            for (int kk = 0; kk < 2; ++kk)
                bh[j][kk] = *(const bf16x8*)(Bs + (wn + j * 16 + l16) * 64 +
                                             (((kk * 4 + quad) ^ swz8) * 8));
        if (t + 1 < NT) stage(bSrc, Bsn, 1, t + 1);
        BARRIER();
        __builtin_amdgcn_s_setprio(1);
#pragma unroll
        for (int i = 0; i < 4; ++i)
#pragma unroll
            for (int j = 0; j < 2; ++j) {
                acc[i][j] = MFMA16(ah[i][0], bh[j][0], acc[i][j]);
                acc[i][j] = MFMA16(ah[i][1], bh[j][1], acc[i][j]);
            }
        __builtin_amdgcn_s_setprio(0);
        BARRIER();

        // ---- phase 1: read b[2..3]; stage A1(t+1)
#pragma unroll
        for (int j = 2; j < 4; ++j)
#pragma unroll
            for (int kk = 0; kk < 2; ++kk)
                bh[j][kk] = *(const bf16x8*)(Bs + (wn + j * 16 + l16) * 64 +
                                             (((kk * 4 + quad) ^ swz8) * 8));
        if (t + 1 < NT) stage(aSrc, Asn, 1, t + 1);
        BARRIER();
        __builtin_amdgcn_s_setprio(1);
#pragma unroll
        for (int i = 0; i < 4; ++i)
#pragma unroll
            for (int j = 2; j < 4; ++j) {
                acc[i][j] = MFMA16(ah[i][0], bh[j][0], acc[i][j]);
                acc[i][j] = MFMA16(ah[i][1], bh[j][1], acc[i][j]);
            }
        __builtin_amdgcn_s_setprio(0);
        BARRIER();

        // ---- phase 2: read a[4..7]; stage B0(t+2) into CURRENT buffer
#pragma unroll
        for (int i = 0; i < 4; ++i)
#pragma unroll
            for (int kk = 0; kk < 2; ++kk)
                ah[i][kk] = *(const bf16x8*)(As + (wm + 64 + i * 16 + l16) * 64 +
                                             (((kk * 4 + quad) ^ swz8) * 8));
        if (t + 2 < NT) stage(bSrc, Bs, 0, t + 2);
        BARRIER();
        __builtin_amdgcn_s_setprio(1);
#pragma unroll
        for (int i = 0; i < 4; ++i)
#pragma unroll
            for (int j = 0; j < 2; ++j) {
                acc[4 + i][j] = MFMA16(ah[i][0], bh[j][0], acc[4 + i][j]);
                acc[4 + i][j] = MFMA16(ah[i][1], bh[j][1], acc[4 + i][j]);
            }
        __builtin_amdgcn_s_setprio(0);
        BARRIER();

        // ---- phase 3: stage A0(t+2); MFMA; counted vmcnt BEFORE the barrier
        if (t + 2 < NT) stage(aSrc, As, 0, t + 2);
        BARRIER();
        __builtin_amdgcn_s_setprio(1);
#pragma unroll
        for (int i = 0; i < 4; ++i)
#pragma unroll
            for (int j = 2; j < 4; ++j) {
                acc[4 + i][j] = MFMA16(ah[i][0], bh[j][0], acc[4 + i][j]);
                acc[4 + i][j] = MFMA16(ah[i][1], bh[j][1], acc[4 + i][j]);
            }
        __builtin_amdgcn_s_setprio(0);
        if (t + 2 < NT) asm volatile("s_waitcnt vmcnt(4)" ::: "memory");
        else            asm volatile("s_waitcnt vmcnt(0)" ::: "memory");
        BARRIER();
    }

    if (MODE == 0 && proj == 2) {
        // V epilogue: per-wave transpose 128(m) x 64(n) -> Vt[B,H,D,S].
        __bf16* wb = smem + wave * 4608;
        const int b_ = bm >> 11;
        const int p8 = lane >> 3, c8 = lane & 7;
#pragma unroll
        for (int ih = 0; ih < 2; ++ih) {
#pragma unroll
            for (int j = 0; j < 4; ++j) {
                const int n = (bn + wn + j * 16 + l16) & (DM - 1);
                const float bia = bias[n];
#pragma unroll
                for (int ii = 0; ii < 4; ++ii) {
                    bf16x4 pk;
#pragma unroll
                    for (int r = 0; r < 4; ++r)
                        pk[r] = (__bf16)(acc[ih * 4 + ii][j][r] + bia);
                    *(bf16x4*)(wb + (j * 16 + l16) * 72 + ii * 16 + quad * 4) = pk;
                }
            }
            // read rows along m, 16B-coalesced stores along s
#pragma unroll
            for (int p = 0; p < 8; ++p) {
                const int d_loc = p * 8 + p8;
                const int n = (bn + wn + d_loc) & (DM - 1);
                const int h = n >> 7, d = n & (HD - 1);
                bf16x8 v = *(const bf16x8*)(wb + d_loc * 72 + c8 * 8);
                const int s = (bm & (SEQ - 1)) + wm + ih * 64 + c8 * 8;
                *(bf16x8*)(Vt_ + ((size_t)((b_ * NH + h) * HD + d)) * SEQ + s) = v;
            }
        }
        return;
    }

    if (MODE == 0) {
        __bf16* out = (__bf16*)Cout_ + (size_t)proj * MROWS * DM;
#pragma unroll
        for (int i = 0; i < 8; ++i) {
            const int m = bm + wm + i * 16 + quad * 4;
            const int b_ = m >> 11, s0 = m & (SEQ - 1);
#pragma unroll
            for (int j = 0; j < 4; ++j) {
                const int n = (bn + wn + j * 16 + l16) & (DM - 1);
                const int h = n >> 7, d = n & (HD - 1);
                const float bia = bias[n];
#pragma unroll
                for (int r = 0; r < 4; ++r)
                    out[((size_t)((b_ * NH + h) * SEQ + s0 + r)) * HD + d] =
                        (__bf16)(acc[i][j][r] + bia);
            }
        }
    } else {
        float* out = (float*)Cout_;
#pragma unroll
        for (int i = 0; i < 8; ++i) {
            const int m = bm + wm + i * 16 + quad * 4;
#pragma unroll
            for (int j = 0; j < 4; ++j) {
                const int n = bn + wn + j * 16 + l16;
                const float bia = bias[n];
#pragma unroll
                for (int r = 0; r < 4; ++r)
                    out[(size_t)(m + r) * DM + n] = acc[i][j][r] + bia;
            }
        }
    }
}

// ---------------------------------------------------------------------------
// Flash attention fwd, causal — frozen from round 4 (XCD-locality decode:
// gid = 64a + 8b + c -> XCD c serves bh in [8c,8c+8); all 16 q-blocks of a
// bh pin to one XCD's L2). 128 q/block, 8 waves x 16 q, 1-deep K/V pipeline.
// ---------------------------------------------------------------------------
__global__ __launch_bounds__(512) void fa_fwd(const __bf16* __restrict__ Q,
                                              const __bf16* __restrict__ Kg,
                                              const __bf16* __restrict__ Vt,
                                              __bf16* __restrict__ O) {
    __shared__ __bf16 Ks[64 * 128];     // [key][d] swizzled       16KB
    __shared__ __bf16 Vs[128 * 64];     // [d][key] swizzled       16KB
    __shared__ __bf16 Pt[8][16 * 72];   // per-wave P^T as [q][key] 18KB
    const int tid  = threadIdx.x;
    const int wave = tid >> 6, lane = tid & 63;
    const int quad = lane >> 4, l16 = lane & 15;
    // XCD-locality decode: gid = 64a + 8b + c -> bx = 15-a, bh = c*8 + b
    const int gid = blockIdx.x;
    const int bx  = 15 - (gid >> 6);
    const int bh  = ((gid & 7) << 3) | ((gid >> 3) & 7);
    const int q0 = bx * 128;
    const int qrow0 = q0 + wave * 16;   // this wave's 16 query rows
    __bf16* Pw = &Pt[wave][0];

    // staging lambdas: 2 x g2l16 each; LDS slot chunk c holds global chunk
    // c^(row&7) (both-sides swizzle, rule #21)
    auto stageK = [&](int k0s) {
#pragma unroll
        for (int j = 0; j < 2; ++j) {
            const int reg  = wave * 2 + j;
            const int rowK = reg * 4 + (lane >> 4);           // 0..63
            const int cK   = (lane & 15) ^ (rowK & 7);        // 16B chunk 0..15
            g2l16(Kg + (size_t)(bh * SEQ + k0s + rowK) * HD + cK * 8, Ks + reg * 512);
        }
    };
    auto stageV = [&](int k0s) {
#pragma unroll
        for (int j = 0; j < 2; ++j) {
            const int reg  = wave * 2 + j;
            const int rowV = reg * 8 + (lane >> 3);           // 0..127
            const int cV   = (lane & 7) ^ (rowV & 7);         // 16B chunk 0..7
            g2l16(Vt + (size_t)(bh * HD + rowV) * SEQ + k0s + cV * 8, Vs + reg * 512);
        }
    };

    // Q B-fragments: lane holds Q[qrow0+l16][kc*32+quad*8..+7]
    bf16x8 qf[4];
    const __bf16* qrow = Q + (size_t)(bh * SEQ + qrow0 + l16) * HD;
#pragma unroll
    for (int kc = 0; kc < 4; ++kc) qf[kc] = *(const bf16x8*)(qrow + kc * 32 + quad * 8);

    float m_q = -INFINITY, l_q = 0.f;   // per-lane: query q = qrow0 + l16
    f32x4 oacc[8];                      // O^T: d = ot*16 + quad*4 + r, q = l16
#pragma unroll
    for (int ot = 0; ot < 8; ++ot) oacc[ot] = (f32x4){0.f, 0.f, 0.f, 0.f};

    const float sl2 = 0.08838834764831845f * 1.4426950408889634f;  // scale*log2(e)

    // prologue: tile 0 in flight; publish K(0), keep V(0) in flight
    stageK(0);
    stageV(0);
    asm volatile("s_waitcnt vmcnt(2)" ::: "memory");
    BARRIER();

    const int ntiles = bx * 2 + 2;      // keys up to q0+127
    for (int kt = 0; kt < ntiles; ++kt) {
        const int k0 = kt * 64;
        const bool work = (k0 <= qrow0 + 15);
        const int swz = l16 & 7;
        f32x4 st[4];

        // ---- S^T = K Q^T (scaled): tile t rows = keys t*16+quad*4+r, col q=l16
        if (work) {
            __builtin_amdgcn_s_setprio(1);
#pragma unroll
            for (int t = 0; t < 4; ++t) {
                f32x4 a = (f32x4){0.f, 0.f, 0.f, 0.f};
#pragma unroll
                for (int kc = 0; kc < 4; ++kc) {
                    bf16x8 kf = *(const bf16x8*)(Ks + (t * 16 + l16) * 128 +
                                                 (((kc * 4 + quad) ^ swz) * 8));
                    a = MFMA16(kf, qf[kc], a);        // A = K, B = Q
                }
#pragma unroll
                for (int r = 0; r < 4; ++r) st[t][r] = a[r] * sl2;
            }
            __builtin_amdgcn_s_setprio(0);
        }
        asm volatile("s_waitcnt lgkmcnt(0)" ::: "memory");  // own Ks reads done
        BARRIER();                                          // B1: Ks free
        if (kt + 1 < ntiles) stageK(k0 + 64);               // prefetch K(t+1)

        if (work) {
            // ---- causal mask (diagonal only lives in the last two tiles)
            if (kt >= ntiles - 2) {
                const int q = qrow0 + l16;
#pragma unroll
                for (int t = 0; t < 4; ++t)
#pragma unroll
                    for (int r = 0; r < 4; ++r) {
                        const int key = k0 + t * 16 + quad * 4 + r;
                        if (key > q) st[t][r] = -INFINITY;
                    }
            }
            // ---- online softmax over keys (regs + quads)
            float vm = st[0][0];
#pragma unroll
            for (int t = 0; t < 4; ++t)
#pragma unroll
                for (int r = 0; r < 4; ++r) vm = fmaxf(vm, st[t][r]);
            vm = fmaxf(vm, __shfl_xor(vm, 16));
            vm = fmaxf(vm, __shfl_xor(vm, 32));
            const float mn = fmaxf(m_q, vm);
            const float alpha = __builtin_amdgcn_exp2f(m_q - mn);
            m_q = mn;
            float ps = 0.f;
#pragma unroll
            for (int t = 0; t < 4; ++t)
#pragma unroll
                for (int r = 0; r < 4; ++r) {
                    const float p = __builtin_amdgcn_exp2f(st[t][r] - mn);
                    st[t][r] = p;
                    ps += p;
                }
            ps += __shfl_xor(ps, 16);
            ps += __shfl_xor(ps, 32);
            l_q = l_q * alpha + ps;
#pragma unroll
            for (int ot = 0; ot < 8; ++ot)
#pragma unroll
                for (int r = 0; r < 4; ++r) oacc[ot][r] *= alpha;

            // ---- P^T rows: lane writes 4 consecutive keys at row q=l16 (b64)
#pragma unroll
            for (int t = 0; t < 4; ++t) {
                bf16x4 pk;
#pragma unroll
                for (int r = 0; r < 4; ++r) pk[r] = (__bf16)st[t][r];
                *(bf16x4*)(Pw + l16 * 72 + t * 16 + quad * 4) = pk;
            }
        }
        // publish V(t): own V loads are the 2 oldest outstanding (K(t+1) stays)
        if (kt + 1 < ntiles) asm volatile("s_waitcnt vmcnt(2)" ::: "memory");
        else                 asm volatile("s_waitcnt vmcnt(0)" ::: "memory");
        BARRIER();                                          // B2: V(t) visible

        if (work) {
            // ---- O^T += V^T P^T
            __builtin_amdgcn_s_setprio(1);
#pragma unroll
            for (int kk = 0; kk < 2; ++kk) {
                bf16x8 pf = *(const bf16x8*)(Pw + l16 * 72 + kk * 32 + quad * 8);
#pragma unroll
                for (int ot = 0; ot < 8; ++ot) {
                    bf16x8 vf = *(const bf16x8*)(Vs + (ot * 16 + l16) * 64 +
                                                 (((kk * 4 + quad) ^ swz) * 8));
                    oacc[ot] = MFMA16(vf, pf, oacc[ot]);   // A = V^T, B = P^T
                }
            }
            __builtin_amdgcn_s_setprio(0);
        }
        asm volatile("s_waitcnt lgkmcnt(0)" ::: "memory");  // own Vs reads done
        BARRIER();                                          // B3: Vs free
        if (kt + 1 < ntiles) {
            stageV(k0 + 64);                                // prefetch V(t+1)
            asm volatile("s_waitcnt vmcnt(2)" ::: "memory");// K(t+1) landed
        }
        BARRIER();                                          // B4: K(t+1) visible
    }

    // epilogue: O[b, s=qrow0+l16, h*128 + d], d = ot*16 + quad*4 + r (8B stores)
    const int b = bh >> 4, h = bh & (NH - 1);
    const float inv = 1.0f / l_q;
    __bf16* orow = O + ((size_t)(b * SEQ + qrow0 + l16)) * DM + h * HD;
#pragma unroll
    for (int ot = 0; ot < 8; ++ot) {
        bf16x4 ov;
#pragma unroll
        for (int r = 0; r < 4; ++r) ov[r] = (__bf16)(oacc[ot][r] * inv);
        *(bf16x4*)(orow + ot * 16 + quad * 4) = ov;
    }
}

// ---------------------------------------------------------------------------
extern "C" void kernel_launch(void* const* d_in, const int* in_sizes, int n_in,
                              void* d_out, int out_size, void* d_ws, size_t ws_size,
                              hipStream_t stream) {
    (void)in_sizes; (void)n_in; (void)out_size; (void)ws_size;
    const float* x  = (const float*)d_in[0];
    const float* Wq = (const float*)d_in[1];
    const float* bq = (const float*)d_in[2];
    const float* Wk = (const float*)d_in[3];
    const float* bk = (const float*)d_in[4];
    const float* Wv = (const float*)d_in[5];
    const float* bv = (const float*)d_in[6];
    const float* Wo = (const float*)d_in[7];
    const float* bo = (const float*)d_in[8];

    char* ws = (char*)d_ws;
    const size_t WT = (size_t)DM * DM * 2;      // 8 MB per transposed bf16 weight
    const size_t XB = (size_t)MROWS * DM * 2;   // 33.5 MB per bf16 activation
    __bf16* WTs = (__bf16*)ws;                  // WqT;WkT;WvT;WoT contiguous
    __bf16* WoT = (__bf16*)(ws + 3 * WT);
    __bf16* xb  = (__bf16*)(ws + 4 * WT + 0 * XB);
    __bf16* Qb  = (__bf16*)(ws + 4 * WT + 1 * XB);  // Qb/Kb contiguous
    __bf16* Kb  = (__bf16*)(ws + 4 * WT + 2 * XB);
    __bf16* Vtb = (__bf16*)(ws + 4 * WT + 3 * XB);  // V written directly as [B,H,D,S]
    __bf16* Ob  = xb;   // x is dead after the QKV projection

    const dim3 tb(32, 8);
    prep_fused<<<16384 + 8192, tb, 0, stream>>>(x, Wq, Wk, Wv, Wo, xb, WTs);

    // Fused QKV projection: [8192,2048] x [2048,6144]; V lands pre-transposed
    gemm_bt<0><<<dim3(32, 24), 512, 0, stream>>>(xb, WTs, bq, bk, bv, Qb, Vtb);

    // 1-D grid, XCD-locality decode inside the kernel (16 q-tiles x 64 bh)
    fa_fwd<<<dim3(1024), 512, 0, stream>>>(Qb, Kb, Vtb, Ob);

    gemm_bt<1><<<dim3(32, 8), 512, 0, stream>>>(Ob, WoT, bo, nullptr, nullptr,
                                                (float*)d_out, nullptr);
}

// Round 7
// 506.120 us; speedup vs baseline: 1.0766x; 1.0439x over previous
//
#include <hip/hip_runtime.h>
#include <hip/hip_bf16.h>
#include <math.h>

// Problem constants (CausalSelfAttention: B=4, S=2048, Dm=2048, H=16, Hd=128)
#define SEQ   2048
#define DM    2048
#define NH    16
#define HD    128
#define MROWS 8192   // B*S

typedef __bf16 bf16x8 __attribute__((ext_vector_type(8)));
typedef __bf16 bf16x4 __attribute__((ext_vector_type(4)));
typedef float  f32x4  __attribute__((ext_vector_type(4)));

#define MFMA16(a, b, c) __builtin_amdgcn_mfma_f32_16x16x32_bf16((a), (b), (c), 0, 0, 0)

__device__ __forceinline__ void g2l16(const void* g, void* l) {
    __builtin_amdgcn_global_load_lds(
        (const __attribute__((address_space(1))) void*)g,
        (__attribute__((address_space(3))) void*)l, 16, 0, 0);
}

// Compile-time memory fence + raw barrier: NO vmcnt drain in the loops.
#define SFENCE() asm volatile("" ::: "memory")
#define BARRIER() do { SFENCE(); __builtin_amdgcn_s_barrier(); SFENCE(); } while (0)

// ---------------------------------------------------------------------------
// Fused prep: blocks [0,16384): transpose+convert the 4 weights
//             blocks [16384, 24576): elementwise x fp32->bf16
// ---------------------------------------------------------------------------
__global__ void prep_fused(const float* __restrict__ x,
                           const float* __restrict__ s0,
                           const float* __restrict__ s1,
                           const float* __restrict__ s2,
                           const float* __restrict__ s3,
                           __bf16* __restrict__ xb,
                           __bf16* __restrict__ wdst) {
    const int bx = blockIdx.x;
    if (bx < 16384) {
        __shared__ float t[32][33];
        const int z = bx >> 12, rem = bx & 4095;
        const float* src = (z == 0) ? s0 : (z == 1) ? s1 : (z == 2) ? s2 : s3;
        __bf16* d = wdst + (size_t)z * DM * DM;
        const int c0 = (rem & 63) * 32, r0 = (rem >> 6) * 32;
        for (int i = threadIdx.y; i < 32; i += 8)
            t[i][threadIdx.x] = src[(size_t)(r0 + i) * DM + c0 + threadIdx.x];
        __syncthreads();
        for (int i = threadIdx.y; i < 32; i += 8)
            d[(size_t)(c0 + i) * DM + r0 + threadIdx.x] = (__bf16)t[threadIdx.x][i];
    } else {
        const int tid = threadIdx.y * 32 + threadIdx.x;
        const size_t i0 = (((size_t)(bx - 16384)) * 256 + tid) * 8;
        if (i0 + 8 <= (size_t)MROWS * DM) {
            f32x4 a = *(const f32x4*)(x + i0);
            f32x4 b = *(const f32x4*)(x + i0 + 4);
            bf16x8 o;
#pragma unroll
            for (int j = 0; j < 4; ++j) { o[j] = (__bf16)a[j]; o[4 + j] = (__bf16)b[j]; }
            *(bf16x8*)(xb + i0) = o;
        }
    }
}

// ---------------------------------------------------------------------------
// GEMM, 256x256 template, XCD-region mapping (r6: FETCH 405->147 MB), now with
// MINIMAL BARRIERS (3 per K-tile instead of 8). Hazard audit (RAW/WAR per LDS
// buffer) shows only these are load-bearing:
//   BAR_A (after b-reads+MFMA ph0/ph1): orders stage-B0(t+2) after all waves'
//         b[0..3] reads of cur Bs.
//   BAR_B (after a[4..7] reads+MFMA ph2): orders stage-A0(t+2) after all
//         waves' a-reads of cur As.
//   BAR_C (after vmcnt(4)): publishes tile t+1's staged data block-wide.
// The removed pre-MFMA barriers enforced read/MFMA lockstep across waves —
// deleting them lets one wave's ds_reads overlap another's MFMAs (and gives
// setprio role diversity to arbitrate, T5).
// Ledger unchanged: per-iter issue order B1(t+1),A1(t+1),B0(t+2),A0(t+2);
// vmcnt(4) at region3 end lands all of t+1, leaves t+2's 4 loads in flight.
// MODE 0: fused QKV (Bt=[3*DM,DM]); Q/K -> [2][B,H,S,D] bf16; V -> Vt[B,H,D,S].
// MODE 1: final proj, fp32 out [M,DM].
// ---------------------------------------------------------------------------
template <int MODE>
__global__ __launch_bounds__(512, 2) void gemm_bt(const __bf16* __restrict__ A,
                                                  const __bf16* __restrict__ Bt,
                                                  const float* __restrict__ b0,
                                                  const float* __restrict__ b1,
                                                  const float* __restrict__ b2,
                                                  void* __restrict__ Cout_,
                                                  __bf16* __restrict__ Vt_) {
    constexpr int K  = DM;
    constexpr int NT = K / 64;                 // 32 K-tiles
    __shared__ __align__(16) __bf16 smem[65536];   // 128 KiB
    const int tid  = threadIdx.x;
    const int wave = tid >> 6, lane = tid & 63;
    const int quad = lane >> 4, l16 = lane & 15;
    const int wm = (wave >> 2) * 128, wn = (wave & 3) * 64;

    // XCD-region mapping (requires gridDim.x == 32, nwg % 8 == 0; true both modes)
    const int wg = blockIdx.y * gridDim.x + blockIdx.x;
    const int xc = wg & 7;                 // XCD (dispatch round-robins on wg%8)
    const int q_ = wg >> 3;                // index within XCD
    const int bm = (xc * 4 + (q_ & 3)) * 256;   // 4 L2-resident A panels per XCD
    const int bn = (q_ >> 2) * 256;             // B panel streamed once per XCD

    const int proj = (MODE == 0) ? (bn >> 11) : 0;              // block-uniform
    const float* bias = (MODE == 0) ? (proj == 0 ? b0 : (proj == 1 ? b1 : b2)) : b0;

    // staging: slot chunk c holds global chunk c^(row&7); row&7 == lane>>3 here
    const int r8   = lane >> 3;
    const int cSrc = (lane & 7) ^ r8;
    const __bf16* aSrc = A  + (size_t)(bm + wave * 8 + r8) * K + cSrc * 8;
    const __bf16* bSrc = Bt + (size_t)(bn + wave * 8 + r8) * K + cSrc * 8;
    const int ldsW = wave * 8 * 64;            // wave-uniform LDS base (elements)

    __bf16* As0 = smem;          __bf16* Bs0 = smem + 16384;
    __bf16* As1 = smem + 32768;  __bf16* Bs1 = smem + 49152;

    // one half-tile stage = 2 x g2l16 per thread (128 rows x 64 cols bf16)
    auto stage = [&](const __bf16* srcLane, __bf16* dstTile, int half, int t) {
#pragma unroll
        for (int q = 0; q < 2; ++q) {
            const int rr = half * 128 + q * 64;
            g2l16(srcLane + (size_t)rr * K + t * 64, dstTile + rr * 64 + ldsW);
        }
    };

    f32x4 acc[8][4];
#pragma unroll
    for (int i = 0; i < 8; ++i)
#pragma unroll
        for (int j = 0; j < 4; ++j) acc[i][j] = (f32x4){0.f, 0.f, 0.f, 0.f};

    // prologue: B0(0) A0(0) B1(0) A1(0) B0(1) A0(1); tile0 landed after vmcnt(4)
    stage(bSrc, Bs0, 0, 0);
    stage(aSrc, As0, 0, 0);
    stage(bSrc, Bs0, 1, 0);
    stage(aSrc, As0, 1, 0);
    if (NT > 1) { stage(bSrc, Bs1, 0, 1); stage(aSrc, As1, 0, 1); }
    asm volatile("s_waitcnt vmcnt(4)" ::: "memory");
    BARRIER();

    const int swz8 = l16 & 7;
    bf16x8 ah[4][2], bh[4][2];

    for (int t = 0; t < NT; ++t) {
        __bf16* As  = (t & 1) ? As1 : As0;
        __bf16* Bs  = (t & 1) ? Bs1 : Bs0;
        __bf16* Asn = (t & 1) ? As0 : As1;
        __bf16* Bsn = (t & 1) ? Bs0 : Bs1;

        // ==== region 1 (old ph0+ph1, no internal barriers):
        //      16 ds_reads + 2 next-tile stages + 32 MFMA
#pragma unroll
        for (int i = 0; i < 4; ++i)
#pragma unroll
            for (int kk = 0; kk < 2; ++kk)
                ah[i][kk] = *(const bf16x8*)(As + (wm + i * 16 + l16) * 64 +
                                             (((kk * 4 + quad) ^ swz8) * 8));
#pragma unroll
        for (int j = 0; j < 4; ++j)
#pragma unroll
            for (int kk = 0; kk < 2; ++kk)
                bh[j][kk] = *(const bf16x8*)(Bs + (wn + j * 16 + l16) * 64 +
                                             (((kk * 4 + quad) ^ swz8) * 8));
        if (t + 1 < NT) { stage(bSrc, Bsn, 1, t + 1); stage(aSrc, Asn, 1, t + 1); }
        __builtin_amdgcn_s_setprio(1);
#pragma unroll
        for (int i = 0; i < 4; ++i)
#pragma unroll
            for (int j = 0; j < 4; ++j) {
                acc[i][j] = MFMA16(ah[i][0], bh[j][0], acc[i][j]);
                acc[i][j] = MFMA16(ah[i][1], bh[j][1], acc[i][j]);
            }
        __builtin_amdgcn_s_setprio(0);
        BARRIER();   // BAR_A: all waves' b-reads of cur Bs complete

        // ==== region 2 (old ph2): 8 ds_reads + stage B0(t+2) + 16 MFMA
#pragma unroll
        for (int i = 0; i < 4; ++i)
#pragma unroll
            for (int kk = 0; kk < 2; ++kk)
                ah[i][kk] = *(const bf16x8*)(As + (wm + 64 + i * 16 + l16) * 64 +
                                             (((kk * 4 + quad) ^ swz8) * 8));
        if (t + 2 < NT) stage(bSrc, Bs, 0, t + 2);
        __builtin_amdgcn_s_setprio(1);
#pragma unroll
        for (int i = 0; i < 4; ++i)
#pragma unroll
            for (int j = 0; j < 2; ++j) {
                acc[4 + i][j] = MFMA16(ah[i][0], bh[j][0], acc[4 + i][j]);
                acc[4 + i][j] = MFMA16(ah[i][1], bh[j][1], acc[4 + i][j]);
            }
        __builtin_amdgcn_s_setprio(0);
        BARRIER();   // BAR_B: all waves' a-reads of cur As complete

        // ==== region 3 (old ph3): stage A0(t+2) + 16 MFMA + counted vmcnt
        if (t + 2 < NT) stage(aSrc, As, 0, t + 2);
        __builtin_amdgcn_s_setprio(1);
#pragma unroll
        for (int i = 0; i < 4; ++i)
#pragma unroll
            for (int j = 2; j < 4; ++j) {
                acc[4 + i][j] = MFMA16(ah[i][0], bh[j][0], acc[4 + i][j]);
                acc[4 + i][j] = MFMA16(ah[i][1], bh[j][1], acc[4 + i][j]);
            }
        __builtin_amdgcn_s_setprio(0);
        if (t + 2 < NT) asm volatile("s_waitcnt vmcnt(4)" ::: "memory");
        else            asm volatile("s_waitcnt vmcnt(0)" ::: "memory");
        BARRIER();   // BAR_C: tile t+1 published block-wide
    }

    if (MODE == 0 && proj == 2) {
        // V epilogue: per-wave transpose 128(m) x 64(n) -> Vt[B,H,D,S].
        __bf16* wb = smem + wave * 4608;
        const int b_ = bm >> 11;
        const int p8 = lane >> 3, c8 = lane & 7;
#pragma unroll
        for (int ih = 0; ih < 2; ++ih) {
#pragma unroll
            for (int j = 0; j < 4; ++j) {
                const int n = (bn + wn + j * 16 + l16) & (DM - 1);
                const float bia = bias[n];
#pragma unroll
                for (int ii = 0; ii < 4; ++ii) {
                    bf16x4 pk;
#pragma unroll
                    for (int r = 0; r < 4; ++r)
                        pk[r] = (__bf16)(acc[ih * 4 + ii][j][r] + bia);
                    *(bf16x4*)(wb + (j * 16 + l16) * 72 + ii * 16 + quad * 4) = pk;
                }
            }
            // read rows along m, 16B-coalesced stores along s
#pragma unroll
            for (int p = 0; p < 8; ++p) {
                const int d_loc = p * 8 + p8;
                const int n = (bn + wn + d_loc) & (DM - 1);
                const int h = n >> 7, d = n & (HD - 1);
                bf16x8 v = *(const bf16x8*)(wb + d_loc * 72 + c8 * 8);
                const int s = (bm & (SEQ - 1)) + wm + ih * 64 + c8 * 8;
                *(bf16x8*)(Vt_ + ((size_t)((b_ * NH + h) * HD + d)) * SEQ + s) = v;
            }
        }
        return;
    }

    if (MODE == 0) {
        __bf16* out = (__bf16*)Cout_ + (size_t)proj * MROWS * DM;
#pragma unroll
        for (int i = 0; i < 8; ++i) {
            const int m = bm + wm + i * 16 + quad * 4;
            const int b_ = m >> 11, s0 = m & (SEQ - 1);
#pragma unroll
            for (int j = 0; j < 4; ++j) {
                const int n = (bn + wn + j * 16 + l16) & (DM - 1);
                const int h = n >> 7, d = n & (HD - 1);
                const float bia = bias[n];
#pragma unroll
                for (int r = 0; r < 4; ++r)
                    out[((size_t)((b_ * NH + h) * SEQ + s0 + r)) * HD + d] =
                        (__bf16)(acc[i][j][r] + bia);
            }
        }
    } else {
        float* out = (float*)Cout_;
#pragma unroll
        for (int i = 0; i < 8; ++i) {
            const int m = bm + wm + i * 16 + quad * 4;
#pragma unroll
            for (int j = 0; j < 4; ++j) {
                const int n = bn + wn + j * 16 + l16;
                const float bia = bias[n];
#pragma unroll
                for (int r = 0; r < 4; ++r)
                    out[(size_t)(m + r) * DM + n] = acc[i][j][r] + bia;
            }
        }
    }
}

// ---------------------------------------------------------------------------
// Flash attention fwd, causal — frozen from round 4 (XCD-locality decode:
// gid = 64a + 8b + c -> XCD c serves bh in [8c,8c+8); all 16 q-blocks of a
// bh pin to one XCD's L2). 128 q/block, 8 waves x 16 q, 1-deep K/V pipeline.
// ---------------------------------------------------------------------------
__global__ __launch_bounds__(512) void fa_fwd(const __bf16* __restrict__ Q,
                                              const __bf16* __restrict__ Kg,
                                              const __bf16* __restrict__ Vt,
                                              __bf16* __restrict__ O) {
    __shared__ __bf16 Ks[64 * 128];     // [key][d] swizzled       16KB
    __shared__ __bf16 Vs[128 * 64];     // [d][key] swizzled       16KB
    __shared__ __bf16 Pt[8][16 * 72];   // per-wave P^T as [q][key] 18KB
    const int tid  = threadIdx.x;
    const int wave = tid >> 6, lane = tid & 63;
    const int quad = lane >> 4, l16 = lane & 15;
    // XCD-locality decode: gid = 64a + 8b + c -> bx = 15-a, bh = c*8 + b
    const int gid = blockIdx.x;
    const int bx  = 15 - (gid >> 6);
    const int bh  = ((gid & 7) << 3) | ((gid >> 3) & 7);
    const int q0 = bx * 128;
    const int qrow0 = q0 + wave * 16;   // this wave's 16 query rows
    __bf16* Pw = &Pt[wave][0];

    // staging lambdas: 2 x g2l16 each; LDS slot chunk c holds global chunk
    // c^(row&7) (both-sides swizzle, rule #21)
    auto stageK = [&](int k0s) {
#pragma unroll
        for (int j = 0; j < 2; ++j) {
            const int reg  = wave * 2 + j;
            const int rowK = reg * 4 + (lane >> 4);           // 0..63
            const int cK   = (lane & 15) ^ (rowK & 7);        // 16B chunk 0..15
            g2l16(Kg + (size_t)(bh * SEQ + k0s + rowK) * HD + cK * 8, Ks + reg * 512);
        }
    };
    auto stageV = [&](int k0s) {
#pragma unroll
        for (int j = 0; j < 2; ++j) {
            const int reg  = wave * 2 + j;
            const int rowV = reg * 8 + (lane >> 3);           // 0..127
            const int cV   = (lane & 7) ^ (rowV & 7);         // 16B chunk 0..7
            g2l16(Vt + (size_t)(bh * HD + rowV) * SEQ + k0s + cV * 8, Vs + reg * 512);
        }
    };

    // Q B-fragments: lane holds Q[qrow0+l16][kc*32+quad*8..+7]
    bf16x8 qf[4];
    const __bf16* qrow = Q + (size_t)(bh * SEQ + qrow0 + l16) * HD;
#pragma unroll
    for (int kc = 0; kc < 4; ++kc) qf[kc] = *(const bf16x8*)(qrow + kc * 32 + quad * 8);

    float m_q = -INFINITY, l_q = 0.f;   // per-lane: query q = qrow0 + l16
    f32x4 oacc[8];                      // O^T: d = ot*16 + quad*4 + r, q = l16
#pragma unroll
    for (int ot = 0; ot < 8; ++ot) oacc[ot] = (f32x4){0.f, 0.f, 0.f, 0.f};

    const float sl2 = 0.08838834764831845f * 1.4426950408889634f;  // scale*log2(e)

    // prologue: tile 0 in flight; publish K(0), keep V(0) in flight
    stageK(0);
    stageV(0);
    asm volatile("s_waitcnt vmcnt(2)" ::: "memory");
    BARRIER();

    const int ntiles = bx * 2 + 2;      // keys up to q0+127
    for (int kt = 0; kt < ntiles; ++kt) {
        const int k0 = kt * 64;
        const bool work = (k0 <= qrow0 + 15);
        const int swz = l16 & 7;
        f32x4 st[4];

        // ---- S^T = K Q^T (scaled): tile t rows = keys t*16+quad*4+r, col q=l16
        if (work) {
            __builtin_amdgcn_s_setprio(1);
#pragma unroll
            for (int t = 0; t < 4; ++t) {
                f32x4 a = (f32x4){0.f, 0.f, 0.f, 0.f};
#pragma unroll
                for (int kc = 0; kc < 4; ++kc) {
                    bf16x8 kf = *(const bf16x8*)(Ks + (t * 16 + l16) * 128 +
                                                 (((kc * 4 + quad) ^ swz) * 8));
                    a = MFMA16(kf, qf[kc], a);        // A = K, B = Q
                }
#pragma unroll
                for (int r = 0; r < 4; ++r) st[t][r] = a[r] * sl2;
            }
            __builtin_amdgcn_s_setprio(0);
        }
        asm volatile("s_waitcnt lgkmcnt(0)" ::: "memory");  // own Ks reads done
        BARRIER();                                          // B1: Ks free
        if (kt + 1 < ntiles) stageK(k0 + 64);               // prefetch K(t+1)

        if (work) {
            // ---- causal mask (diagonal only lives in the last two tiles)
            if (kt >= ntiles - 2) {
                const int q = qrow0 + l16;
#pragma unroll
                for (int t = 0; t < 4; ++t)
#pragma unroll
                    for (int r = 0; r < 4; ++r) {
                        const int key = k0 + t * 16 + quad * 4 + r;
                        if (key > q) st[t][r] = -INFINITY;
                    }
            }
            // ---- online softmax over keys (regs + quads)
            float vm = st[0][0];
#pragma unroll
            for (int t = 0; t < 4; ++t)
#pragma unroll
                for (int r = 0; r < 4; ++r) vm = fmaxf(vm, st[t][r]);
            vm = fmaxf(vm, __shfl_xor(vm, 16));
            vm = fmaxf(vm, __shfl_xor(vm, 32));
            const float mn = fmaxf(m_q, vm);
            const float alpha = __builtin_amdgcn_exp2f(m_q - mn);
            m_q = mn;
            float ps = 0.f;
#pragma unroll
            for (int t = 0; t < 4; ++t)
#pragma unroll
                for (int r = 0; r < 4; ++r) {
                    const float p = __builtin_amdgcn_exp2f(st[t][r] - mn);
                    st[t][r] = p;
                    ps += p;
                }
            ps += __shfl_xor(ps, 16);
            ps += __shfl_xor(ps, 32);
            l_q = l_q * alpha + ps;
#pragma unroll
            for (int ot = 0; ot < 8; ++ot)
#pragma unroll
                for (int r = 0; r < 4; ++r) oacc[ot][r] *= alpha;

            // ---- P^T rows: lane writes 4 consecutive keys at row q=l16 (b64)
#pragma unroll
            for (int t = 0; t < 4; ++t) {
                bf16x4 pk;
#pragma unroll
                for (int r = 0; r < 4; ++r) pk[r] = (__bf16)st[t][r];
                *(bf16x4*)(Pw + l16 * 72 + t * 16 + quad * 4) = pk;
            }
        }
        // publish V(t): own V loads are the 2 oldest outstanding (K(t+1) stays)
        if (kt + 1 < ntiles) asm volatile("s_waitcnt vmcnt(2)" ::: "memory");
        else                 asm volatile("s_waitcnt vmcnt(0)" ::: "memory");
        BARRIER();                                          // B2: V(t) visible

        if (work) {
            // ---- O^T += V^T P^T
            __builtin_amdgcn_s_setprio(1);
#pragma unroll
            for (int kk = 0; kk < 2; ++kk) {
                bf16x8 pf = *(const bf16x8*)(Pw + l16 * 72 + kk * 32 + quad * 8);
#pragma unroll
                for (int ot = 0; ot < 8; ++ot) {
                    bf16x8 vf = *(const bf16x8*)(Vs + (ot * 16 + l16) * 64 +
                                                 (((kk * 4 + quad) ^ swz) * 8));
                    oacc[ot] = MFMA16(vf, pf, oacc[ot]);   // A = V^T, B = P^T
                }
            }
            __builtin_amdgcn_s_setprio(0);
        }
        asm volatile("s_waitcnt lgkmcnt(0)" ::: "memory");  // own Vs reads done
        BARRIER();                                          // B3: Vs free
        if (kt + 1 < ntiles) {
            stageV(k0 + 64);                                // prefetch V(t+1)
            asm volatile("s_waitcnt vmcnt(2)" ::: "memory");// K(t+1) landed
        }
        BARRIER();                                          // B4: K(t+1) visible
    }

    // epilogue: O[b, s=qrow0+l16, h*128 + d], d = ot*16 + quad*4 + r (8B stores)
    const int b = bh >> 4, h = bh & (NH - 1);
    const float inv = 1.0f / l_q;
    __bf16* orow = O + ((size_t)(b * SEQ + qrow0 + l16)) * DM + h * HD;
#pragma unroll
    for (int ot = 0; ot < 8; ++ot) {
        bf16x4 ov;
#pragma unroll
        for (int r = 0; r < 4; ++r) ov[r] = (__bf16)(oacc[ot][r] * inv);
        *(bf16x4*)(orow + ot * 16 + quad * 4) = ov;
    }
}

// ---------------------------------------------------------------------------
extern "C" void kernel_launch(void* const* d_in, const int* in_sizes, int n_in,
                              void* d_out, int out_size, void* d_ws, size_t ws_size,
                              hipStream_t stream) {
    (void)in_sizes; (void)n_in; (void)out_size; (void)ws_size;
    const float* x  = (const float*)d_in[0];
    const float* Wq = (const float*)d_in[1];
    const float* bq = (const float*)d_in[2];
    const float* Wk = (const float*)d_in[3];
    const float* bk = (const float*)d_in[4];
    const float* Wv = (const float*)d_in[5];
    const float* bv = (const float*)d_in[6];
    const float* Wo = (const float*)d_in[7];
    const float* bo = (const float*)d_in[8];

    char* ws = (char*)d_ws;
    const size_t WT = (size_t)DM * DM * 2;      // 8 MB per transposed bf16 weight
    const size_t XB = (size_t)MROWS * DM * 2;   // 33.5 MB per bf16 activation
    __bf16* WTs = (__bf16*)ws;                  // WqT;WkT;WvT;WoT contiguous
    __bf16* WoT = (__bf16*)(ws + 3 * WT);
    __bf16* xb  = (__bf16*)(ws + 4 * WT + 0 * XB);
    __bf16* Qb  = (__bf16*)(ws + 4 * WT + 1 * XB);  // Qb/Kb contiguous
    __bf16* Kb  = (__bf16*)(ws + 4 * WT + 2 * XB);
    __bf16* Vtb = (__bf16*)(ws + 4 * WT + 3 * XB);  // V written directly as [B,H,D,S]
    __bf16* Ob  = xb;   // x is dead after the QKV projection

    const dim3 tb(32, 8);
    prep_fused<<<16384 + 8192, tb, 0, stream>>>(x, Wq, Wk, Wv, Wo, xb, WTs);

    // Fused QKV projection: [8192,2048] x [2048,6144]; V lands pre-transposed
    gemm_bt<0><<<dim3(32, 24), 512, 0, stream>>>(xb, WTs, bq, bk, bv, Qb, Vtb);

    // 1-D grid, XCD-locality decode inside the kernel (16 q-tiles x 64 bh)
    fa_fwd<<<dim3(1024), 512, 0, stream>>>(Qb, Kb, Vtb, Ob);

    gemm_bt<1><<<dim3(32, 8), 512, 0, stream>>>(Ob, WoT, bo, nullptr, nullptr,
                                                (float*)d_out, nullptr);
}